// Round 1
// baseline (699.191 us; speedup 1.0000x reference)
//
#include <hip/hip_runtime.h>
#include <math.h>

#define TT 1024   // tokens
#define HH 1024   // hidden
#define MM 512    // moe intermediate
#define NE 16     // experts
// TOP_K = 2, SCALE = 2.5, NORM_TOPK = true

// ---------------- router: scores, top-2, per-expert dispatch lists ----------------
__global__ __launch_bounds__(256) void router_k(
    const float* __restrict__ x, const float* __restrict__ gate_w,
    int* __restrict__ counts, int* __restrict__ token_list, float* __restrict__ weight_list)
{
    const int wave = threadIdx.x >> 6;
    const int lane = threadIdx.x & 63;
    const int t = (blockIdx.x << 2) + wave;
    const float* xr = x + (size_t)t * HH;
    float xv[16];
#pragma unroll
    for (int i = 0; i < 16; ++i) xv[i] = xr[lane + (i << 6)];
    float sc[NE];
#pragma unroll
    for (int e = 0; e < NE; ++e) {
        const float* gr = gate_w + e * HH;
        float acc = 0.f;
#pragma unroll
        for (int i = 0; i < 16; ++i) acc = fmaf(xv[i], gr[lane + (i << 6)], acc);
#pragma unroll
        for (int off = 32; off > 0; off >>= 1) acc += __shfl_down(acc, off, 64);
        sc[e] = acc;   // valid on lane 0
    }
    if (lane == 0) {
        // sigmoid is monotonic -> top-2 on logits; first-index-wins on ties (matches lax.top_k)
        float l1 = -1e30f, l2 = -1e30f; int i1 = 0, i2 = 0;
#pragma unroll
        for (int e = 0; e < NE; ++e) {
            float v = sc[e];
            if (v > l1) { l2 = l1; i2 = i1; l1 = v; i1 = e; }
            else if (v > l2) { l2 = v; i2 = e; }
        }
        float w1 = 1.f / (1.f + __expf(-l1));
        float w2 = 1.f / (1.f + __expf(-l2));
        const float inv = 2.5f / (w1 + w2 + 1e-20f);
        w1 *= inv; w2 *= inv;
        int s1 = atomicAdd(&counts[i1], 1);
        token_list[i1 * TT + s1] = t;
        weight_list[i1 * TT + s1] = w1;
        int s2 = atomicAdd(&counts[i2], 1);
        token_list[i2 * TT + s2] = t;
        weight_list[i2 * TT + s2] = w2;
    }
}

__global__ void prefix_k(const int* __restrict__ counts, int* __restrict__ offs)
{
    if (threadIdx.x == 0 && blockIdx.x == 0) {
        int acc = 0;
#pragma unroll
        for (int e = 0; e < NE; ++e) { offs[e] = acc; acc += counts[e]; }
        offs[NE] = acc;
    }
}

// ---------------- shared expert: inter = silu(x@ws_gate) * (x@ws_up) ----------------
__global__ __launch_bounds__(256) void sgu_k(
    const float* __restrict__ x, const float* __restrict__ wg, const float* __restrict__ wu,
    float* __restrict__ inter)
{
    __shared__ float xs[64][17];
    __shared__ float bgs[16][64];
    __shared__ float bus[16][64];
    const int tid = threadIdx.x;
    const int row0 = blockIdx.x << 6;
    const int col0 = blockIdx.y << 6;
    const int lr = tid >> 2, lc = (tid & 3) << 2;
    const int br = tid >> 4, bc = (tid & 15) << 2;
    const int tr = (tid >> 4) << 2, tc = (tid & 15) << 2;
    const float* arow = x + (size_t)(row0 + lr) * HH;
    const float* bgrow = wg + (size_t)br * MM + col0 + bc;
    const float* burow = wu + (size_t)br * MM + col0 + bc;
    float accg[4][4] = {{0}}, accu[4][4] = {{0}};
    for (int k0 = 0; k0 < HH; k0 += 16) {
        float4 av = *(const float4*)(arow + k0 + lc);
        xs[lr][lc] = av.x; xs[lr][lc + 1] = av.y; xs[lr][lc + 2] = av.z; xs[lr][lc + 3] = av.w;
        *(float4*)&bgs[br][bc] = *(const float4*)(bgrow + (size_t)k0 * MM);
        *(float4*)&bus[br][bc] = *(const float4*)(burow + (size_t)k0 * MM);
        __syncthreads();
#pragma unroll
        for (int kk = 0; kk < 16; ++kk) {
            float a[4] = { xs[tr][kk], xs[tr + 1][kk], xs[tr + 2][kk], xs[tr + 3][kk] };
            float4 g4 = *(const float4*)&bgs[kk][tc];
            float4 u4 = *(const float4*)&bus[kk][tc];
            float gb[4] = { g4.x, g4.y, g4.z, g4.w };
            float ub[4] = { u4.x, u4.y, u4.z, u4.w };
#pragma unroll
            for (int i = 0; i < 4; ++i)
#pragma unroll
                for (int j = 0; j < 4; ++j) {
                    accg[i][j] = fmaf(a[i], gb[j], accg[i][j]);
                    accu[i][j] = fmaf(a[i], ub[j], accu[i][j]);
                }
        }
        __syncthreads();
    }
#pragma unroll
    for (int i = 0; i < 4; ++i) {
        float* orow = inter + (size_t)(row0 + tr + i) * MM + col0 + tc;
#pragma unroll
        for (int j = 0; j < 4; ++j) {
            float g = accg[i][j];
            float s = g / (1.f + __expf(-g));
            orow[j] = s * accu[i][j];
        }
    }
}

// ---------------- shared expert down: out = inter @ ws_down (direct store) ----------------
__global__ __launch_bounds__(256) void sdown_k(
    const float* __restrict__ inter, const float* __restrict__ wd, float* __restrict__ out)
{
    __shared__ float as[64][17];
    __shared__ float bs[16][64];
    const int tid = threadIdx.x;
    const int row0 = blockIdx.x << 6;
    const int col0 = blockIdx.y << 6;
    const int lr = tid >> 2, lc = (tid & 3) << 2;
    const int br = tid >> 4, bc = (tid & 15) << 2;
    const int tr = (tid >> 4) << 2, tc = (tid & 15) << 2;
    const float* arow = inter + (size_t)(row0 + lr) * MM;
    const float* brow = wd + (size_t)br * HH + col0 + bc;
    float acc[4][4] = {{0}};
    for (int k0 = 0; k0 < MM; k0 += 16) {
        float4 av = *(const float4*)(arow + k0 + lc);
        as[lr][lc] = av.x; as[lr][lc + 1] = av.y; as[lr][lc + 2] = av.z; as[lr][lc + 3] = av.w;
        *(float4*)&bs[br][bc] = *(const float4*)(brow + (size_t)k0 * HH);
        __syncthreads();
#pragma unroll
        for (int kk = 0; kk < 16; ++kk) {
            float a[4] = { as[tr][kk], as[tr + 1][kk], as[tr + 2][kk], as[tr + 3][kk] };
            float4 b4 = *(const float4*)&bs[kk][tc];
            float bb[4] = { b4.x, b4.y, b4.z, b4.w };
#pragma unroll
            for (int i = 0; i < 4; ++i)
#pragma unroll
                for (int j = 0; j < 4; ++j)
                    acc[i][j] = fmaf(a[i], bb[j], acc[i][j]);
        }
        __syncthreads();
    }
#pragma unroll
    for (int i = 0; i < 4; ++i) {
        float* orow = out + (size_t)(row0 + tr + i) * HH + col0 + tc;
#pragma unroll
        for (int j = 0; j < 4; ++j) orow[j] = acc[i][j];
    }
}

// ---------------- routed gate/up (grouped, gathered rows) ----------------
__global__ __launch_bounds__(256) void rgu_k(
    const float* __restrict__ x, const float* __restrict__ w_gate, const float* __restrict__ w_up,
    const int* __restrict__ counts, const int* __restrict__ offs,
    const int* __restrict__ token_list, float* __restrict__ rinter)
{
    const int e = blockIdx.z;
    const int cnt = counts[e];
    const int r0 = blockIdx.x << 6;
    if (r0 >= cnt) return;
    const int col0 = blockIdx.y << 6;
    __shared__ float xs[64][17];
    __shared__ float bgs[16][64];
    __shared__ float bus[16][64];
    __shared__ int toks[64];
    const int tid = threadIdx.x;
    if (tid < 64) {
        int i = r0 + tid; if (i >= cnt) i = cnt - 1;
        toks[tid] = token_list[e * TT + i];
    }
    __syncthreads();
    const int lr = tid >> 2, lc = (tid & 3) << 2;
    const int br = tid >> 4, bc = (tid & 15) << 2;
    const int tr = (tid >> 4) << 2, tc = (tid & 15) << 2;
    const float* arow = x + (size_t)toks[lr] * HH;
    const float* bgrow = w_gate + (size_t)e * HH * MM + (size_t)br * MM + col0 + bc;
    const float* burow = w_up + (size_t)e * HH * MM + (size_t)br * MM + col0 + bc;
    float accg[4][4] = {{0}}, accu[4][4] = {{0}};
    for (int k0 = 0; k0 < HH; k0 += 16) {
        float4 av = *(const float4*)(arow + k0 + lc);
        xs[lr][lc] = av.x; xs[lr][lc + 1] = av.y; xs[lr][lc + 2] = av.z; xs[lr][lc + 3] = av.w;
        *(float4*)&bgs[br][bc] = *(const float4*)(bgrow + (size_t)k0 * MM);
        *(float4*)&bus[br][bc] = *(const float4*)(burow + (size_t)k0 * MM);
        __syncthreads();
#pragma unroll
        for (int kk = 0; kk < 16; ++kk) {
            float a[4] = { xs[tr][kk], xs[tr + 1][kk], xs[tr + 2][kk], xs[tr + 3][kk] };
            float4 g4 = *(const float4*)&bgs[kk][tc];
            float4 u4 = *(const float4*)&bus[kk][tc];
            float gb[4] = { g4.x, g4.y, g4.z, g4.w };
            float ub[4] = { u4.x, u4.y, u4.z, u4.w };
#pragma unroll
            for (int i = 0; i < 4; ++i)
#pragma unroll
                for (int j = 0; j < 4; ++j) {
                    accg[i][j] = fmaf(a[i], gb[j], accg[i][j]);
                    accu[i][j] = fmaf(a[i], ub[j], accu[i][j]);
                }
        }
        __syncthreads();
    }
    const int ob = offs[e] + r0;
#pragma unroll
    for (int i = 0; i < 4; ++i) {
        if (r0 + tr + i < cnt) {
            float* orow = rinter + (size_t)(ob + tr + i) * MM + col0 + tc;
#pragma unroll
            for (int j = 0; j < 4; ++j) {
                float g = accg[i][j];
                float s = g / (1.f + __expf(-g));
                orow[j] = s * accu[i][j];
            }
        }
    }
}

// ---------------- routed down: out[token] += weight * (rinter @ w_down[e]) ----------------
__global__ __launch_bounds__(256) void rdown_k(
    const float* __restrict__ rinter, const float* __restrict__ w_down,
    const int* __restrict__ counts, const int* __restrict__ offs,
    const int* __restrict__ token_list, const float* __restrict__ weight_list,
    float* __restrict__ out)
{
    const int e = blockIdx.z;
    const int cnt = counts[e];
    const int r0 = blockIdx.x << 6;
    if (r0 >= cnt) return;
    const int col0 = blockIdx.y << 6;
    __shared__ float as[64][17];
    __shared__ float bs[16][64];
    const int tid = threadIdx.x;
    const int lr = tid >> 2, lc = (tid & 3) << 2;
    const int br = tid >> 4, bc = (tid & 15) << 2;
    const int tr = (tid >> 4) << 2, tc = (tid & 15) << 2;
    const int ob = offs[e];
    int ir = r0 + lr; if (ir >= cnt) ir = cnt - 1;
    const float* arow = rinter + (size_t)(ob + ir) * MM;
    const float* brow = w_down + (size_t)e * MM * HH + (size_t)br * HH + col0 + bc;
    float acc[4][4] = {{0}};
    for (int k0 = 0; k0 < MM; k0 += 16) {
        float4 av = *(const float4*)(arow + k0 + lc);
        as[lr][lc] = av.x; as[lr][lc + 1] = av.y; as[lr][lc + 2] = av.z; as[lr][lc + 3] = av.w;
        *(float4*)&bs[br][bc] = *(const float4*)(brow + (size_t)k0 * HH);
        __syncthreads();
#pragma unroll
        for (int kk = 0; kk < 16; ++kk) {
            float a[4] = { as[tr][kk], as[tr + 1][kk], as[tr + 2][kk], as[tr + 3][kk] };
            float4 b4 = *(const float4*)&bs[kk][tc];
            float bb[4] = { b4.x, b4.y, b4.z, b4.w };
#pragma unroll
            for (int i = 0; i < 4; ++i)
#pragma unroll
                for (int j = 0; j < 4; ++j)
                    acc[i][j] = fmaf(a[i], bb[j], acc[i][j]);
        }
        __syncthreads();
    }
#pragma unroll
    for (int i = 0; i < 4; ++i) {
        int row = r0 + tr + i;
        if (row < cnt) {
            int t = token_list[e * TT + row];
            float w = weight_list[e * TT + row];
            float* orow = out + (size_t)t * HH + col0 + tc;
#pragma unroll
            for (int j = 0; j < 4; ++j) atomicAdd(&orow[j], w * acc[i][j]);
        }
    }
}

extern "C" void kernel_launch(void* const* d_in, const int* in_sizes, int n_in,
                              void* d_out, int out_size, void* d_ws, size_t ws_size,
                              hipStream_t stream)
{
    const float* x       = (const float*)d_in[0];
    const float* gate_w  = (const float*)d_in[1];
    const float* w_gate  = (const float*)d_in[2];
    const float* w_up    = (const float*)d_in[3];
    const float* w_down  = (const float*)d_in[4];
    const float* ws_gate = (const float*)d_in[5];
    const float* ws_up   = (const float*)d_in[6];
    const float* ws_down = (const float*)d_in[7];
    float* out = (float*)d_out;

    // workspace layout (all 4-byte elems): counts[16] | offs[17] (at +16) | pad to 64 |
    // token_list[16*1024] | weight_list[16*1024] | inter[1024*512] | rinter[2048*512]
    int* counts = (int*)d_ws;
    int* offs = counts + 16;
    int* token_list = counts + 64;
    float* weight_list = (float*)(counts + 64 + NE * TT);
    float* inter = (float*)(counts + 64 + 2 * NE * TT);
    float* rinter = inter + (size_t)TT * MM;

    hipMemsetAsync(counts, 0, 64, stream);
    router_k<<<dim3(TT / 4), 256, 0, stream>>>(x, gate_w, counts, token_list, weight_list);
    prefix_k<<<1, 64, 0, stream>>>(counts, offs);
    sgu_k<<<dim3(16, 8), 256, 0, stream>>>(x, ws_gate, ws_up, inter);
    sdown_k<<<dim3(16, 16), 256, 0, stream>>>(inter, ws_down, out);
    rgu_k<<<dim3(16, 8, NE), 256, 0, stream>>>(x, w_gate, w_up, counts, offs, token_list, rinter);
    rdown_k<<<dim3(16, 16, NE), 256, 0, stream>>>(rinter, w_down, counts, offs, token_list, weight_list, out);
}

// Round 2
// 206.046 us; speedup vs baseline: 3.3934x; 3.3934x over previous
//
#include <hip/hip_runtime.h>
#include <math.h>

#define TT 1024   // tokens
#define HH 1024   // hidden
#define MM 512    // moe intermediate
#define NE 16     // routed experts (expert NE == shared)
// TOP_K = 2, SCALE = 2.5, NORM_TOPK = true

typedef _Float16 f16;
typedef _Float16 f16x4 __attribute__((ext_vector_type(4)));
typedef _Float16 f16x8 __attribute__((ext_vector_type(8)));
typedef float f32x4 __attribute__((ext_vector_type(4)));

// XOR swizzle on fp16 column index: flips bits 3..5 (16B-block granular for b128,
// 8B-granular ok for b64 since only bits>=3 change)
#define SWZ(r, k) ((k) ^ (((r) & 7) << 3))

// ---------------- router: scores, top-2, per-expert dispatch lists ----------------
__global__ __launch_bounds__(256) void router_k(
    const float* __restrict__ x, const float* __restrict__ gate_w,
    int* __restrict__ counts, int* __restrict__ token_list, float* __restrict__ weight_list)
{
    const int wave = threadIdx.x >> 6;
    const int lane = threadIdx.x & 63;
    const int t = (blockIdx.x << 2) + wave;
    const float* xr = x + (size_t)t * HH;
    float xv[16];
#pragma unroll
    for (int i = 0; i < 16; ++i) xv[i] = xr[lane + (i << 6)];
    float sc[NE];
#pragma unroll
    for (int e = 0; e < NE; ++e) {
        const float* gr = gate_w + e * HH;
        float acc = 0.f;
#pragma unroll
        for (int i = 0; i < 16; ++i) acc = fmaf(xv[i], gr[lane + (i << 6)], acc);
#pragma unroll
        for (int off = 32; off > 0; off >>= 1) acc += __shfl_down(acc, off, 64);
        sc[e] = acc;   // valid on lane 0
    }
    if (lane == 0) {
        // sigmoid monotonic -> top-2 on logits; first-index-wins on ties (matches lax.top_k)
        float l1 = -1e30f, l2 = -1e30f; int i1 = 0, i2 = 0;
#pragma unroll
        for (int e = 0; e < NE; ++e) {
            float v = sc[e];
            if (v > l1) { l2 = l1; i2 = i1; l1 = v; i1 = e; }
            else if (v > l2) { l2 = v; i2 = e; }
        }
        float w1 = 1.f / (1.f + __expf(-l1));
        float w2 = 1.f / (1.f + __expf(-l2));
        const float inv = 2.5f / (w1 + w2 + 1e-20f);
        w1 *= inv; w2 *= inv;
        int s1 = atomicAdd(&counts[i1], 1);
        token_list[i1 * TT + s1] = t;
        weight_list[i1 * TT + s1] = w1;
        int s2 = atomicAdd(&counts[i2], 1);
        token_list[i2 * TT + s2] = t;
        weight_list[i2 * TT + s2] = w2;
    }
}

__global__ void prefix_k(const int* __restrict__ counts, int* __restrict__ offs)
{
    if (threadIdx.x == 0 && blockIdx.x == 0) {
        int acc = 0;
#pragma unroll
        for (int e = 0; e < NE; ++e) { offs[e] = acc; acc += counts[e]; }
        offs[NE] = acc;
    }
}

// ---------------- fused gate/up: rinter[slot] = f16( silu(x@Wg) * (x@Wu) ) ----------------
// z = expert (NE == shared); 64x64 output tile, BK=64, f16 MFMA 16x16x32
__global__ __launch_bounds__(256) void gu_k(
    const float* __restrict__ x,
    const float* __restrict__ w_gate, const float* __restrict__ w_up,
    const float* __restrict__ ws_gate, const float* __restrict__ ws_up,
    const int* __restrict__ counts, const int* __restrict__ offs,
    const int* __restrict__ token_list, f16* __restrict__ rinter)
{
    const int e = blockIdx.z;
    int cnt, slot0;
    const float *wgp, *wup;
    if (e < NE) {
        cnt = counts[e]; slot0 = offs[e];
        wgp = w_gate + (size_t)e * HH * MM;
        wup = w_up   + (size_t)e * HH * MM;
    } else {
        cnt = TT; slot0 = 2 * TT;           // shared expert: identity routing
        wgp = ws_gate; wup = ws_up;
    }
    const int r0 = blockIdx.x << 6;
    if (r0 >= cnt) return;
    const int n0 = blockIdx.y << 6;

    __shared__ f16 As[64][64];
    __shared__ f16 Bgs[64][64];   // [n][k] (transposed)
    __shared__ f16 Bus[64][64];
    __shared__ int toks[64];

    const int tid = threadIdx.x;
    if (tid < 64) {
        int i = r0 + tid; if (i >= cnt) i = cnt - 1;
        toks[tid] = (e < NE) ? token_list[e * TT + i] : i;
    }
    __syncthreads();

    // staging assignments
    const int ar  = tid >> 2;            // A row 0..63 (4 threads/row)
    const int akb = (tid & 3) << 2;      // A k-base; loads at akb + 16*u (coalesced per u)
    const int bk  = (tid >> 4) << 2;     // B unit k-base 0..60
    const int bn  = (tid & 15) << 2;     // B unit n-base 0..60
    // wave/fragment assignment
    const int w = tid >> 6, l = tid & 63;
    const int wr = (w >> 1) << 5, wc = (w & 1) << 5;
    const int lm = l & 15, lg = l >> 4;

    f32x4 accg[2][2] = {{{0}}}, accu[2][2] = {{{0}}};
    const float* arow = x + (size_t)toks[ar] * HH;

    for (int k0 = 0; k0 < HH; k0 += 64) {
        // stage A (gathered rows, fp32 -> f16)
#pragma unroll
        for (int u = 0; u < 4; ++u) {
            int k = akb + (u << 4);
            float4 v = *(const float4*)(arow + k0 + k);
            f16x4 h = { (f16)v.x, (f16)v.y, (f16)v.z, (f16)v.w };
            *(f16x4*)&As[ar][SWZ(ar, k)] = h;
        }
        // stage B gate+up: 4x4 register micro-transpose -> Bs[n][k]
        {
            const float* g0 = wgp + (size_t)(k0 + bk) * MM + n0 + bn;
            const float* u0 = wup + (size_t)(k0 + bk) * MM + n0 + bn;
            float4 g[4], uu[4];
#pragma unroll
            for (int i = 0; i < 4; ++i) {
                g[i]  = *(const float4*)(g0 + (size_t)i * MM);
                uu[i] = *(const float4*)(u0 + (size_t)i * MM);
            }
#pragma unroll
            for (int j = 0; j < 4; ++j) {
                f16x4 hg = { (f16)((&g[0].x)[j]),  (f16)((&g[1].x)[j]),  (f16)((&g[2].x)[j]),  (f16)((&g[3].x)[j]) };
                f16x4 hu = { (f16)((&uu[0].x)[j]), (f16)((&uu[1].x)[j]), (f16)((&uu[2].x)[j]), (f16)((&uu[3].x)[j]) };
                *(f16x4*)&Bgs[bn + j][SWZ(bn + j, bk)] = hg;
                *(f16x4*)&Bus[bn + j][SWZ(bn + j, bk)] = hu;
            }
        }
        __syncthreads();
#pragma unroll
        for (int h = 0; h < 2; ++h) {
            const int kk = (h << 5) + (lg << 3);
            f16x8 a[2], bg[2], bu[2];
#pragma unroll
            for (int f = 0; f < 2; ++f) {
                int m = wr + (f << 4) + lm;
                a[f]  = *(const f16x8*)&As[m][SWZ(m, kk)];
                int n = wc + (f << 4) + lm;
                bg[f] = *(const f16x8*)&Bgs[n][SWZ(n, kk)];
                bu[f] = *(const f16x8*)&Bus[n][SWZ(n, kk)];
            }
#pragma unroll
            for (int fi = 0; fi < 2; ++fi)
#pragma unroll
                for (int fj = 0; fj < 2; ++fj) {
                    accg[fi][fj] = __builtin_amdgcn_mfma_f32_16x16x32_f16(a[fi], bg[fj], accg[fi][fj], 0, 0, 0);
                    accu[fi][fj] = __builtin_amdgcn_mfma_f32_16x16x32_f16(a[fi], bu[fj], accu[fi][fj], 0, 0, 0);
                }
        }
        __syncthreads();
    }
    // epilogue: silu(g)*u -> f16 store; C/D layout col=lane&15, row=(lane>>4)*4+reg
#pragma unroll
    for (int fi = 0; fi < 2; ++fi)
#pragma unroll
        for (int r = 0; r < 4; ++r) {
            int m = wr + (fi << 4) + (lg << 2) + r;
            if (r0 + m < cnt) {
                f16* orow = rinter + (size_t)(slot0 + r0 + m) * MM + n0;
#pragma unroll
                for (int fj = 0; fj < 2; ++fj) {
                    float gg = accg[fi][fj][r], uv = accu[fi][fj][r];
                    float s = gg / (1.f + __expf(-gg));
                    orow[wc + (fj << 4) + lm] = (f16)(s * uv);
                }
            }
        }
}

// ---------------- down: out[token] += weight * (rinter @ Wd)  (shared: weight=1) --------
__global__ __launch_bounds__(256) void down_k(
    const f16* __restrict__ rinter,
    const float* __restrict__ w_down, const float* __restrict__ ws_down,
    const int* __restrict__ counts, const int* __restrict__ offs,
    const int* __restrict__ token_list, const float* __restrict__ weight_list,
    float* __restrict__ out)
{
    const int e = blockIdx.z;
    int cnt, slot0; const float* wdp;
    if (e < NE) { cnt = counts[e]; slot0 = offs[e]; wdp = w_down + (size_t)e * MM * HH; }
    else        { cnt = TT; slot0 = 2 * TT; wdp = ws_down; }
    const int r0 = blockIdx.x << 6;
    if (r0 >= cnt) return;
    const int n0 = blockIdx.y << 6;   // of HH

    __shared__ f16 As[64][64];
    __shared__ f16 Bs[64][64];        // [n][k]

    const int tid = threadIdx.x;
    const int ar  = tid >> 2;
    const int akb = (tid & 3) << 3;   // f16x8 loads at akb + 32*u
    const int bk  = (tid >> 4) << 2;
    const int bn  = (tid & 15) << 2;
    const int w = tid >> 6, l = tid & 63;
    const int wr = (w >> 1) << 5, wc = (w & 1) << 5;
    const int lm = l & 15, lg = l >> 4;

    f32x4 acc[2][2] = {{{0}}};
    int ari = r0 + ar; if (ari >= cnt) ari = cnt - 1;
    const f16* arow = rinter + (size_t)(slot0 + ari) * MM;

    for (int k0 = 0; k0 < MM; k0 += 64) {
        // stage A (already f16): 2 x 16B copies per thread
#pragma unroll
        for (int u = 0; u < 2; ++u) {
            int k = akb + (u << 5);
            f16x8 hv = *(const f16x8*)(arow + k0 + k);
            *(f16x8*)&As[ar][SWZ(ar, k)] = hv;
        }
        // stage B with 4x4 transpose
        {
            const float* b0 = wdp + (size_t)(k0 + bk) * HH + n0 + bn;
            float4 bb[4];
#pragma unroll
            for (int i = 0; i < 4; ++i) bb[i] = *(const float4*)(b0 + (size_t)i * HH);
#pragma unroll
            for (int j = 0; j < 4; ++j) {
                f16x4 hb = { (f16)((&bb[0].x)[j]), (f16)((&bb[1].x)[j]), (f16)((&bb[2].x)[j]), (f16)((&bb[3].x)[j]) };
                *(f16x4*)&Bs[bn + j][SWZ(bn + j, bk)] = hb;
            }
        }
        __syncthreads();
#pragma unroll
        for (int h = 0; h < 2; ++h) {
            const int kk = (h << 5) + (lg << 3);
            f16x8 a[2], b[2];
#pragma unroll
            for (int f = 0; f < 2; ++f) {
                int m = wr + (f << 4) + lm;
                a[f] = *(const f16x8*)&As[m][SWZ(m, kk)];
                int n = wc + (f << 4) + lm;
                b[f] = *(const f16x8*)&Bs[n][SWZ(n, kk)];
            }
#pragma unroll
            for (int fi = 0; fi < 2; ++fi)
#pragma unroll
                for (int fj = 0; fj < 2; ++fj)
                    acc[fi][fj] = __builtin_amdgcn_mfma_f32_16x16x32_f16(a[fi], b[fj], acc[fi][fj], 0, 0, 0);
        }
        __syncthreads();
    }
#pragma unroll
    for (int fi = 0; fi < 2; ++fi)
#pragma unroll
        for (int r = 0; r < 4; ++r) {
            int m = wr + (fi << 4) + (lg << 2) + r;
            int row = r0 + m;
            if (row < cnt) {
                int t; float wt;
                if (e < NE) { t = token_list[e * TT + row]; wt = weight_list[e * TT + row]; }
                else        { t = row; wt = 1.f; }
                float* orow = out + (size_t)t * HH + n0;
#pragma unroll
                for (int fj = 0; fj < 2; ++fj)
                    atomicAdd(&orow[wc + (fj << 4) + lm], wt * acc[fi][fj][r]);
            }
        }
}

extern "C" void kernel_launch(void* const* d_in, const int* in_sizes, int n_in,
                              void* d_out, int out_size, void* d_ws, size_t ws_size,
                              hipStream_t stream)
{
    const float* x       = (const float*)d_in[0];
    const float* gate_w  = (const float*)d_in[1];
    const float* w_gate  = (const float*)d_in[2];
    const float* w_up    = (const float*)d_in[3];
    const float* w_down  = (const float*)d_in[4];
    const float* ws_gate = (const float*)d_in[5];
    const float* ws_up   = (const float*)d_in[6];
    const float* ws_down = (const float*)d_in[7];
    float* out = (float*)d_out;

    // workspace: counts[16] | offs[17] | pad to 64 ints | token_list[16*1024] |
    // weight_list[16*1024] | rinter f16 [3072][512]
    int* counts = (int*)d_ws;
    int* offs = counts + 16;
    int* token_list = counts + 64;
    float* weight_list = (float*)(counts + 64 + NE * TT);
    f16* rinter = (f16*)(counts + 64 + 2 * NE * TT);

    hipMemsetAsync(counts, 0, 64, stream);
    hipMemsetAsync(out, 0, (size_t)TT * HH * sizeof(float), stream);
    router_k<<<dim3(TT / 4), 256, 0, stream>>>(x, gate_w, counts, token_list, weight_list);
    prefix_k<<<1, 64, 0, stream>>>(counts, offs);
    // z: 16 routed experts + 1 shared; x: row tiles (early-exit past cnt); y: col tiles
    gu_k<<<dim3(16, MM / 64, NE + 1), 256, 0, stream>>>(
        x, w_gate, w_up, ws_gate, ws_up, counts, offs, token_list, rinter);
    down_k<<<dim3(16, HH / 64, NE + 1), 256, 0, stream>>>(
        rinter, w_down, ws_down, counts, offs, token_list, weight_list, out);
}